// Round 6
// baseline (4876.324 us; speedup 1.0000x reference)
//
#include <hip/hip_runtime.h>
#include <hip/hip_bf16.h>

#define TT 128
#define BB 256
#define OBSD 1024
#define FEATD 512
#define NA 15
#define DD 528
#define GG 2112   // 4*DD
#define KK 1056   // 2*DD
#define SCL 4096.f
#define INV_SCL (1.f/4096.f)

using half8 = __attribute__((ext_vector_type(8))) _Float16;
using f32x4 = __attribute__((ext_vector_type(4))) float;

__device__ __forceinline__ void split1(float v, _Float16& h, _Float16& l){
  h = (_Float16)v;
  l = (_Float16)((v - (float)h) * SCL);
}
__device__ __forceinline__ float sigf(float x){ return 1.f/(1.f + expf(-x)); }

// global->LDS direct staging. aux=17: device-coherent (executes past local L2,
// safe vs stale per-XCD L2). aux=0: normal cached (L2-resident data: W, x).
#define GLOAD_LDS(g, s, aux) \
  __builtin_amdgcn_global_load_lds((const __attribute__((address_space(1))) void*)(g), \
                                   (__attribute__((address_space(3))) void*)(s), 16, 0, (aux))

// ---------------- prep kernels ----------------

__global__ void k_prep_w(const float* __restrict__ wih, const float* __restrict__ whh,
                         const float* __restrict__ bih, const float* __restrict__ bhh,
                         _Float16* __restrict__ Wh, _Float16* __restrict__ Wl,
                         float* __restrict__ bias){
  const int n = GG*KK;
  for (int i = blockIdx.x*blockDim.x + threadIdx.x; i < n; i += gridDim.x*blockDim.x){
    int r = i / KK, c = i % KK;
    float v = (c < DD) ? wih[r*DD + c] : whh[r*DD + (c - DD)];
    split1(v, Wh[i], Wl[i]);
    if (i < GG) bias[i] = bih[i] + bhh[i];
  }
}

__global__ void k_conv_encw(const float* __restrict__ src,
                            _Float16* __restrict__ dh, _Float16* __restrict__ dl){
  const int n = FEATD*OBSD;
  for (int i = blockIdx.x*blockDim.x + threadIdx.x; i < n; i += gridDim.x*blockDim.x)
    split1(src[i], dh[i], dl[i]);
}

__global__ void k_fill_extra(const float* __restrict__ reward, const int* __restrict__ act,
                             _Float16* __restrict__ xh, _Float16* __restrict__ xl){
  int row = blockIdx.x*blockDim.x + threadIdx.x;
  if (row >= TT*BB) return;
  float r = fminf(1.f, fmaxf(-1.f, reward[row]));
  size_t base = (size_t)row*DD + FEATD;
  _Float16 hh, hl;
  split1(r, hh, hl);
  xh[base] = hh; xl[base] = hl;
  int a = act[row];
  #pragma unroll
  for (int i = 0; i < NA; ++i){
    xh[base+1+i] = (i == a) ? (_Float16)1.0f : (_Float16)0.0f;
    xl[base+1+i] = (_Float16)0.0f;
  }
}

// ---------------- encoder GEMM -> x planes cols 0..511 ----------------
__launch_bounds__(256)
__global__ void k_encoder(const float* __restrict__ obs, const _Float16* __restrict__ ench,
                          const _Float16* __restrict__ encl,
                          const float* __restrict__ encb,
                          _Float16* __restrict__ xh, _Float16* __restrict__ xl){
  __shared__ _Float16 Ah[128][40], Al[128][40], Bh[128][40], Bl[128][40];
  const int mt = blockIdx.x, nt = blockIdx.y;
  const int tid = threadIdx.x, w = tid >> 6, l = tid & 63;
  const int wm = (w >> 1)*64, wn = (w & 1)*64;
  const int m0 = mt*128, n0 = nt*128;
  f32x4 acc1[4][4], acc2[4][4];
  #pragma unroll
  for (int m = 0; m < 4; ++m)
    #pragma unroll
    for (int n = 0; n < 4; ++n)
      #pragma unroll
      for (int q = 0; q < 4; ++q){ acc1[m][n][q]=0.f; acc2[m][n][q]=0.f; }

  for (int k0 = 0; k0 < OBSD; k0 += 32){
    {
      int row = tid >> 1, c0 = (tid & 1)*16;
      const float* src = obs + (size_t)(m0+row)*OBSD + k0 + c0;
      #pragma unroll
      for (int cc = 0; cc < 16; ++cc){
        float v = src[cc];
        split1(v, Ah[row][c0+cc], Al[row][c0+cc]);
      }
      const _Float16* bh = ench + (size_t)(n0+row)*OBSD + k0 + c0;
      const _Float16* bl = encl + (size_t)(n0+row)*OBSD + k0 + c0;
      *(half8*)&Bh[row][c0]   = *(const half8*)(bh);
      *(half8*)&Bh[row][c0+8] = *(const half8*)(bh+8);
      *(half8*)&Bl[row][c0]   = *(const half8*)(bl);
      *(half8*)&Bl[row][c0+8] = *(const half8*)(bl+8);
    }
    __syncthreads();
    half8 ah[4], al[4], bh[4], bl[4];
    #pragma unroll
    for (int m = 0; m < 4; ++m){
      ah[m] = *(const half8*)&Ah[wm + m*16 + (l & 15)][(l >> 4)*8];
      al[m] = *(const half8*)&Al[wm + m*16 + (l & 15)][(l >> 4)*8];
    }
    #pragma unroll
    for (int n = 0; n < 4; ++n){
      bh[n] = *(const half8*)&Bh[wn + n*16 + (l & 15)][(l >> 4)*8];
      bl[n] = *(const half8*)&Bl[wn + n*16 + (l & 15)][(l >> 4)*8];
    }
    #pragma unroll
    for (int m = 0; m < 4; ++m)
      #pragma unroll
      for (int n = 0; n < 4; ++n){
        acc1[m][n] = __builtin_amdgcn_mfma_f32_16x16x32_f16(ah[m], bh[n], acc1[m][n], 0, 0, 0);
        acc2[m][n] = __builtin_amdgcn_mfma_f32_16x16x32_f16(ah[m], bl[n], acc2[m][n], 0, 0, 0);
        acc2[m][n] = __builtin_amdgcn_mfma_f32_16x16x32_f16(al[m], bh[n], acc2[m][n], 0, 0, 0);
      }
    __syncthreads();
  }
  #pragma unroll
  for (int m = 0; m < 4; ++m)
    #pragma unroll
    for (int n = 0; n < 4; ++n)
      #pragma unroll
      for (int q = 0; q < 4; ++q){
        int row = m0 + wm + m*16 + (l >> 4)*4 + q;
        int col = n0 + wn + n*16 + (l & 15);
        float v = acc1[m][n][q] + acc2[m][n][q]*INV_SCL + encb[col];
        v = fmaxf(v, 0.f);
        _Float16 hh, hl;
        split1(v, hh, hl);
        size_t off = (size_t)row*DD + col;
        xh[off] = hh; xl[off] = hl;
      }
}

// ---------------- persistent recurrence kernel ----------------
// 264 blocks launched; roles self-selected so that (under round-robin bid%8 XCD
// dispatch) strip js lands on XCD js%8 -> each XCD's W working set ~2.2-2.7 MB,
// L2-resident across all timesteps. Excess blocks exit immediately.
// Role: mt = 64-row batch tile (0..3), js = 16-wide hidden strip (0..32).
// Depth-7 global_load_lds pipeline, 8 LDS slots, counted vmcnt (24 steady).
__launch_bounds__(256)
__global__ void k_recur(_Float16* xh, _Float16* xl,
                        _Float16* h1h0, _Float16* h1l0,
                        _Float16* h1h1, _Float16* h1l1,
                        const _Float16* __restrict__ Wh0, const _Float16* __restrict__ Wl0,
                        const _Float16* __restrict__ Wh1, const _Float16* __restrict__ Wl1,
                        const float* __restrict__ bias0, const float* __restrict__ bias1,
                        const int* __restrict__ term, int* flags,
                        const _Float16* __restrict__ zp){
  // S[slot][plane][row][col] : plane 0=Ah 1=Al 2=Bh 3=Bl ; [64][32] f16 = 128 KB
  __shared__ _Float16 S[8][4][64][32];

  const int tid = threadIdx.x, w = tid >> 6, l = tid & 63;
  const int b = blockIdx.x;
  const int xcd = b & 7;                 // round-robin XCD heuristic (perf-only)
  const int kk = b >> 3;                 // local index on this XCD: 0..32
  const int nstr = (xcd == 0) ? 5 : 4;   // strips served by this XCD (33 total)
  if (kk >= 4*nstr) return;              // excess block: exit (frees CU)
  const int mt = kk & 3;
  const int js = xcd + 8*(kk >> 2);      // js % 8 == xcd
  const int m0 = mt*64, j0 = js*16;
  const int aRow = m0 + w*16 + (l >> 2);
  const int acol = (l & 3)*8;
  const int wRowH = w*DD + j0 + (l >> 2);    // W row staged by this lane (gate=w)
  const int prow0 = m0 + w*16 + ((l >> 4) << 2);
  const int jcol = j0 + (l & 15);

  float c1r[4] = {0.f,0.f,0.f,0.f};
  float c2r[4] = {0.f,0.f,0.f,0.f};
  f32x4 accm[4], accc[4];

  auto flag_wait = [&](int idx){
    if (tid == 0){
      while (__hip_atomic_load(&flags[idx], __ATOMIC_RELAXED, __HIP_MEMORY_SCOPE_AGENT) < 33)
        __builtin_amdgcn_s_sleep(2);
    }
    __builtin_amdgcn_s_barrier();
    __builtin_amdgcn_sched_barrier(0);
  };
  auto flag_post = [&](int idx){
    asm volatile("s_waitcnt vmcnt(0)" ::: "memory");   // own h stores visible
    __builtin_amdgcn_s_barrier();                      // all threads drained
    if (tid == 0)
      __hip_atomic_fetch_add(&flags[idx], 1, __ATOMIC_RELAXED, __HIP_MEMORY_SCOPE_AGENT);
  };

  auto run_phase = [&](bool isL1,
                       const _Float16* p1h, const _Float16* p1l,
                       const _Float16* p2h, const _Float16* p2l, bool ndA,
                       const _Float16* Wh, const _Float16* Wl,
                       int wA_i, int wA_f, int wB_i, int wB_f){
    #pragma unroll
    for (int g = 0; g < 4; ++g)
      #pragma unroll
      for (int q = 0; q < 4; ++q){ accm[g][q] = 0.f; accc[g][q] = 0.f; }

    auto issue = [&](int i){
      if (i == wA_i && wA_f >= 0) flag_wait(wA_f);
      if (i == wB_i && wB_f >= 0) flag_wait(wB_f);
      const int s = isL1 ? (i < 16 ? 17 + i : i - 16) : i;   // slab order permutation
      const int slot = i & 7;
      const int col = s*32 + acol;
      const _Float16 *gph, *gpl;
      if (col < DD){
        size_t off = (size_t)aRow*DD + col;
        gph = p1h + off; gpl = p1l + off;
      } else if (ndA){
        size_t off = (size_t)aRow*DD + (col - DD);
        gph = p2h + off; gpl = p2l + off;
      } else {
        gph = zp; gpl = zp;
      }
      _Float16* dAh = &S[slot][0][w*16][0];
      _Float16* dAl = &S[slot][1][w*16][0];
      _Float16* dBh = &S[slot][2][w*16][0];
      _Float16* dBl = &S[slot][3][w*16][0];
      const _Float16* gbh = Wh + (size_t)wRowH*KK + col;
      const _Float16* gbl = Wl + (size_t)wRowH*KK + col;
      if (isL1 || s >= 16){   // h-plane data: device-coherent path
        GLOAD_LDS(gph, dAh, 17);
        GLOAD_LDS(gpl, dAl, 17);
      } else {                // pure-x slab: cached
        GLOAD_LDS(gph, dAh, 0);
        GLOAD_LDS(gpl, dAl, 0);
      }
      GLOAD_LDS(gbh, dBh, 0);
      GLOAD_LDS(gbl, dBl, 0);
    };

    issue(0); issue(1); issue(2); issue(3); issue(4); issue(5); issue(6);
    #pragma unroll 1
    for (int i = 0; i < 33; ++i){
      if (i <= 26)      asm volatile("s_waitcnt vmcnt(24)" ::: "memory");
      else if (i == 27) asm volatile("s_waitcnt vmcnt(20)" ::: "memory");
      else if (i == 28) asm volatile("s_waitcnt vmcnt(16)" ::: "memory");
      else if (i == 29) asm volatile("s_waitcnt vmcnt(12)" ::: "memory");
      else if (i == 30) asm volatile("s_waitcnt vmcnt(8)"  ::: "memory");
      else if (i == 31) asm volatile("s_waitcnt vmcnt(4)"  ::: "memory");
      else              asm volatile("s_waitcnt vmcnt(0)"  ::: "memory");
      __builtin_amdgcn_s_barrier();
      __builtin_amdgcn_sched_barrier(0);
      if (i + 7 < 33) issue(i + 7);
      const int slot = i & 7;
      half8 fah = *(const half8*)&S[slot][0][w*16 + (l & 15)][(l >> 4)*8];
      half8 fal = *(const half8*)&S[slot][1][w*16 + (l & 15)][(l >> 4)*8];
      #pragma unroll
      for (int g = 0; g < 4; ++g){
        half8 fbh = *(const half8*)&S[slot][2][g*16 + (l & 15)][(l >> 4)*8];
        half8 fbl = *(const half8*)&S[slot][3][g*16 + (l & 15)][(l >> 4)*8];
        accm[g] = __builtin_amdgcn_mfma_f32_16x16x32_f16(fah, fbh, accm[g], 0, 0, 0);
        accc[g] = __builtin_amdgcn_mfma_f32_16x16x32_f16(fah, fbl, accc[g], 0, 0, 0);
        accc[g] = __builtin_amdgcn_mfma_f32_16x16x32_f16(fal, fbh, accc[g], 0, 0, 0);
      }
    }
  };

  auto epilogue = [&](const float* bias, float* cr, _Float16* dh, _Float16* dl,
                      const int* term_t){
    #pragma unroll
    for (int q = 0; q < 4; ++q){
      const int row = prow0 + q;
      float iv = accm[0][q] + accc[0][q]*INV_SCL + bias[jcol];
      float fv = accm[1][q] + accc[1][q]*INV_SCL + bias[DD + jcol];
      float gv = accm[2][q] + accc[2][q]*INV_SCL + bias[2*DD + jcol];
      float ov = accm[3][q] + accc[3][q]*INV_SCL + bias[3*DD + jcol];
      float cp = (term_t[row] == 0) ? cr[q] : 0.f;
      float cn = sigf(fv)*cp + sigf(iv)*tanhf(gv);
      float hn = sigf(ov)*tanhf(cn);
      cr[q] = cn;
      _Float16 hh, hl;
      split1(hn, hh, hl);
      size_t off = (size_t)row*DD + jcol;
      __hip_atomic_store((unsigned short*)(dh + off), __builtin_bit_cast(unsigned short, hh),
                         __ATOMIC_RELAXED, __HIP_MEMORY_SCOPE_AGENT);
      __hip_atomic_store((unsigned short*)(dl + off), __builtin_bit_cast(unsigned short, hl),
                         __ATOMIC_RELAXED, __HIP_MEMORY_SCOPE_AGENT);
    }
  };

  _Float16* h1h[2] = {h1h0, h1h1};
  _Float16* h1l[2] = {h1l0, h1l1};

  #pragma unroll 1
  for (int t = 0; t < TT; ++t){
    const int* term_t = term + t*BB;
    const bool ndA = (t > 0) && (term_t[aRow] == 0);
    _Float16* xth = xh + (size_t)t*BB*DD;
    _Float16* xtl = xl + (size_t)t*BB*DD;
    const _Float16* xph = xh + (size_t)(t > 0 ? t-1 : 0)*BB*DD;
    const _Float16* xpl = xl + (size_t)(t > 0 ? t-1 : 0)*BB*DD;

    // ===== layer 0: gates = [x(t) | h1(t-1)*nd] @ W0^T =====
    run_phase(false, xth, xtl, h1h[(t+1)&1], h1l[(t+1)&1], ndA, Wh0, Wl0,
              16, (t >= 1) ? (t-1)*8 + mt : -1, -1, -1);
    if (t >= 2) flag_wait((t-2)*8 + 4 + mt);           // WAR on h1 buffer t&1
    epilogue(bias0, c1r, h1h[t&1], h1l[t&1], term_t);
    flag_post(t*8 + mt);

    // ===== layer 1: gates = [h1(t) | h2(t-1)*nd] @ W1^T ; h2(t-1)=x[t-1] alias =====
    run_phase(true, h1h[t&1], h1l[t&1], xph, xpl, ndA, Wh1, Wl1,
              0, (t >= 1) ? (t-1)*8 + 4 + mt : -1,
              16, t*8 + mt);
    epilogue(bias1, c2r, xth, xtl, term_t);            // h2(t) overwrites x[t]
    flag_post(t*8 + 4 + mt);
  }
}

// ---------------- heads: logits/baseline/action ----------------
__launch_bounds__(256)
__global__ void k_heads(const _Float16* __restrict__ oh, const _Float16* __restrict__ ol,
                        const float* __restrict__ polw, const float* __restrict__ basew,
                        const float* __restrict__ polb, const float* __restrict__ baseb,
                        float* __restrict__ dout){
  __shared__ _Float16 Ah[128][40], Al[128][40];
  __shared__ _Float16 Bh[16][552], Bl[16][552];
  const int bid = blockIdx.x;
  const int tid = threadIdx.x, w = tid >> 6, l = tid & 63;
  const int m0 = bid*128;

  for (int i = tid; i < 16*544; i += 256){
    int r = i / 544, c = i % 544;
    float v = 0.f;
    if (c < DD) v = (r < NA) ? polw[r*DD + c] : basew[c];
    split1(v, Bh[r][c], Bl[r][c]);
  }
  __syncthreads();

  f32x4 acc1[2], acc2[2];
  #pragma unroll
  for (int m = 0; m < 2; ++m)
    #pragma unroll
    for (int q = 0; q < 4; ++q){ acc1[m][q]=0.f; acc2[m][q]=0.f; }

  for (int it = 0; it < 17; ++it){
    const int k0 = it*32;
    {
      int row = tid >> 1, c0 = (tid & 1)*16;
      size_t off = (size_t)(m0+row)*DD + k0 + c0;   // overreads pad; B=0 there
      *(half8*)&Ah[row][c0]   = *(const half8*)(oh + off);
      *(half8*)&Ah[row][c0+8] = *(const half8*)(oh + off + 8);
      *(half8*)&Al[row][c0]   = *(const half8*)(ol + off);
      *(half8*)&Al[row][c0+8] = *(const half8*)(ol + off + 8);
    }
    __syncthreads();
    half8 fbh = *(const half8*)&Bh[l & 15][k0 + (l >> 4)*8];
    half8 fbl = *(const half8*)&Bl[l & 15][k0 + (l >> 4)*8];
    #pragma unroll
    for (int m = 0; m < 2; ++m){
      half8 fah = *(const half8*)&Ah[w*32 + m*16 + (l & 15)][(l >> 4)*8];
      half8 fal = *(const half8*)&Al[w*32 + m*16 + (l & 15)][(l >> 4)*8];
      acc1[m] = __builtin_amdgcn_mfma_f32_16x16x32_f16(fah, fbh, acc1[m], 0, 0, 0);
      acc2[m] = __builtin_amdgcn_mfma_f32_16x16x32_f16(fah, fbl, acc2[m], 0, 0, 0);
      acc2[m] = __builtin_amdgcn_mfma_f32_16x16x32_f16(fal, fbh, acc2[m], 0, 0, 0);
    }
    __syncthreads();
  }

  const int a = l & 15;
  const size_t base_off = (size_t)TT*BB*NA;
  const size_t act_off  = base_off + (size_t)TT*BB;
  #pragma unroll
  for (int m = 0; m < 2; ++m)
    #pragma unroll
    for (int q = 0; q < 4; ++q){
      int r = m0 + w*32 + m*16 + (l >> 4)*4 + q;
      float v = acc1[m][q] + acc2[m][q]*INV_SCL + ((a < NA) ? polb[a] : baseb[0]);
      float key = (a < NA) ? v : -3.4e38f;
      int ki = a;
      #pragma unroll
      for (int s = 1; s < 16; s <<= 1){
        float ov = __shfl_xor(key, s, 64);
        int   oi = __shfl_xor(ki,  s, 64);
        if (ov > key || (ov == key && oi < ki)){ key = ov; ki = oi; }
      }
      if (a < NA) dout[(size_t)r*NA + a] = v;
      if (a == NA) dout[base_off + r] = v;
      if (a == 0)  dout[act_off + r] = (float)ki;
    }
}

// ---------------- launch ----------------
extern "C" void kernel_launch(void* const* d_in, const int* in_sizes, int n_in,
                              void* d_out, int out_size, void* d_ws, size_t ws_size,
                              hipStream_t stream){
  const float* obs        = (const float*)d_in[0];
  const int*   last_act   = (const int*)  d_in[1];
  const float* reward     = (const float*)d_in[2];
  const int*   terminated = (const int*)  d_in[3];
  const float* enc_w      = (const float*)d_in[4];
  const float* enc_b      = (const float*)d_in[5];
  const float* w_ih0      = (const float*)d_in[6];
  const float* w_hh0      = (const float*)d_in[7];
  const float* b_ih0      = (const float*)d_in[8];
  const float* b_hh0      = (const float*)d_in[9];
  const float* w_ih1      = (const float*)d_in[10];
  const float* w_hh1      = (const float*)d_in[11];
  const float* b_ih1      = (const float*)d_in[12];
  const float* b_hh1      = (const float*)d_in[13];
  const float* pol_w      = (const float*)d_in[14];
  const float* pol_b      = (const float*)d_in[15];
  const float* base_w     = (const float*)d_in[16];
  const float* base_b     = (const float*)d_in[17];

  char* ws = (char*)d_ws;
  size_t o = 0;
  auto alloc = [&](size_t bytes){ size_t r = o; o += (bytes + 255) & ~(size_t)255; return r; };

  _Float16* Wh0   = (_Float16*)(ws + alloc((size_t)GG*KK*2));
  _Float16* Wl0   = (_Float16*)(ws + alloc((size_t)GG*KK*2));
  _Float16* Wh1   = (_Float16*)(ws + alloc((size_t)GG*KK*2));
  _Float16* Wl1   = (_Float16*)(ws + alloc((size_t)GG*KK*2));
  float* bias0    = (float*)(ws + alloc((size_t)GG*4));
  float* bias1    = (float*)(ws + alloc((size_t)GG*4));
  _Float16* ench  = (_Float16*)(ws + alloc((size_t)FEATD*OBSD*2));
  _Float16* encl  = (_Float16*)(ws + alloc((size_t)FEATD*OBSD*2));
  _Float16* xh    = (_Float16*)(ws + alloc((size_t)TT*BB*DD*2 + 4096));  // x / h2-out hi
  _Float16* xl    = (_Float16*)(ws + alloc((size_t)TT*BB*DD*2 + 4096));  // lo plane
  _Float16* h1h0  = (_Float16*)(ws + alloc((size_t)BB*DD*2));
  _Float16* h1l0  = (_Float16*)(ws + alloc((size_t)BB*DD*2));
  _Float16* h1h1  = (_Float16*)(ws + alloc((size_t)BB*DD*2));
  _Float16* h1l1  = (_Float16*)(ws + alloc((size_t)BB*DD*2));
  int*   flags    = (int*)(ws + alloc((size_t)TT*8*4 + 256));   // + zero page
  _Float16* zp    = (_Float16*)((char*)flags + TT*8*4);

  hipMemsetAsync(flags, 0, (size_t)TT*8*4 + 256, stream);

  k_prep_w<<<2048, 256, 0, stream>>>(w_ih0, w_hh0, b_ih0, b_hh0, Wh0, Wl0, bias0);
  k_prep_w<<<2048, 256, 0, stream>>>(w_ih1, w_hh1, b_ih1, b_hh1, Wh1, Wl1, bias1);
  k_conv_encw<<<2048, 256, 0, stream>>>(enc_w, ench, encl);
  k_fill_extra<<<TT*BB/256, 256, 0, stream>>>(reward, last_act, xh, xl);

  dim3 eg(TT*BB/128, FEATD/128);
  k_encoder<<<eg, 256, 0, stream>>>(obs, ench, encl, enc_b, xh, xl);

  k_recur<<<264, 256, 0, stream>>>(xh, xl, h1h0, h1l0, h1h1, h1l1,
                                   Wh0, Wl0, Wh1, Wl1, bias0, bias1,
                                   terminated, flags, zp);

  k_heads<<<TT*BB/128, 256, 0, stream>>>(xh, xl, pol_w, base_w, pol_b, base_b, (float*)d_out);
}

// Round 7
// 4305.769 us; speedup vs baseline: 1.1325x; 1.1325x over previous
//
#include <hip/hip_runtime.h>
#include <hip/hip_bf16.h>

#define TT 128
#define BB 256
#define OBSD 1024
#define FEATD 512
#define NA 15
#define DD 528
#define GG 2112   // 4*DD
#define KK 1056   // 2*DD
#define SCL 4096.f
#define INV_SCL (1.f/4096.f)

using half8 = __attribute__((ext_vector_type(8))) _Float16;
using f32x4 = __attribute__((ext_vector_type(4))) float;

__device__ __forceinline__ void split1(float v, _Float16& h, _Float16& l){
  h = (_Float16)v;
  l = (_Float16)((v - (float)h) * SCL);
}
__device__ __forceinline__ float sigf(float x){ return 1.f/(1.f + expf(-x)); }
__device__ __forceinline__ int swz(int r){ return (r ^ (r >> 2)) & 3; }

// global->LDS direct staging. aux=17 (SC0|SC1): executes at the device coherence
// point (safe vs stale per-XCD L2). aux=0: normal cached.
#define GLOAD_LDS(g, s, aux) \
  __builtin_amdgcn_global_load_lds((const __attribute__((address_space(1))) void*)(g), \
                                   (__attribute__((address_space(3))) void*)(s), 16, 0, (aux))

// ---------------- prep kernels ----------------

__global__ void k_prep_w(const float* __restrict__ wih, const float* __restrict__ whh,
                         const float* __restrict__ bih, const float* __restrict__ bhh,
                         _Float16* __restrict__ Wh, _Float16* __restrict__ Wl,
                         float* __restrict__ bias){
  const int n = GG*KK;
  for (int i = blockIdx.x*blockDim.x + threadIdx.x; i < n; i += gridDim.x*blockDim.x){
    int r = i / KK, c = i % KK;
    float v = (c < DD) ? wih[r*DD + c] : whh[r*DD + (c - DD)];
    split1(v, Wh[i], Wl[i]);
    if (i < GG) bias[i] = bih[i] + bhh[i];
  }
}

__global__ void k_conv_encw(const float* __restrict__ src,
                            _Float16* __restrict__ dh, _Float16* __restrict__ dl){
  const int n = FEATD*OBSD;
  for (int i = blockIdx.x*blockDim.x + threadIdx.x; i < n; i += gridDim.x*blockDim.x)
    split1(src[i], dh[i], dl[i]);
}

__global__ void k_fill_extra(const float* __restrict__ reward, const int* __restrict__ act,
                             _Float16* __restrict__ xh, _Float16* __restrict__ xl){
  int row = blockIdx.x*blockDim.x + threadIdx.x;
  if (row >= TT*BB) return;
  float r = fminf(1.f, fmaxf(-1.f, reward[row]));
  size_t base = (size_t)row*DD + FEATD;
  _Float16 hh, hl;
  split1(r, hh, hl);
  xh[base] = hh; xl[base] = hl;
  int a = act[row];
  #pragma unroll
  for (int i = 0; i < NA; ++i){
    xh[base+1+i] = (i == a) ? (_Float16)1.0f : (_Float16)0.0f;
    xl[base+1+i] = (_Float16)0.0f;
  }
}

// ---------------- encoder GEMM -> x planes cols 0..511 ----------------
__launch_bounds__(256)
__global__ void k_encoder(const float* __restrict__ obs, const _Float16* __restrict__ ench,
                          const _Float16* __restrict__ encl,
                          const float* __restrict__ encb,
                          _Float16* __restrict__ xh, _Float16* __restrict__ xl){
  __shared__ _Float16 Ah[128][40], Al[128][40], Bh[128][40], Bl[128][40];
  const int mt = blockIdx.x, nt = blockIdx.y;
  const int tid = threadIdx.x, w = tid >> 6, l = tid & 63;
  const int wm = (w >> 1)*64, wn = (w & 1)*64;
  const int m0 = mt*128, n0 = nt*128;
  f32x4 acc1[4][4], acc2[4][4];
  #pragma unroll
  for (int m = 0; m < 4; ++m)
    #pragma unroll
    for (int n = 0; n < 4; ++n)
      #pragma unroll
      for (int q = 0; q < 4; ++q){ acc1[m][n][q]=0.f; acc2[m][n][q]=0.f; }

  for (int k0 = 0; k0 < OBSD; k0 += 32){
    {
      int row = tid >> 1, c0 = (tid & 1)*16;
      const float* src = obs + (size_t)(m0+row)*OBSD + k0 + c0;
      #pragma unroll
      for (int cc = 0; cc < 16; ++cc){
        float v = src[cc];
        split1(v, Ah[row][c0+cc], Al[row][c0+cc]);
      }
      const _Float16* bh = ench + (size_t)(n0+row)*OBSD + k0 + c0;
      const _Float16* bl = encl + (size_t)(n0+row)*OBSD + k0 + c0;
      *(half8*)&Bh[row][c0]   = *(const half8*)(bh);
      *(half8*)&Bh[row][c0+8] = *(const half8*)(bh+8);
      *(half8*)&Bl[row][c0]   = *(const half8*)(bl);
      *(half8*)&Bl[row][c0+8] = *(const half8*)(bl+8);
    }
    __syncthreads();
    half8 ah[4], al[4], bh[4], bl[4];
    #pragma unroll
    for (int m = 0; m < 4; ++m){
      ah[m] = *(const half8*)&Ah[wm + m*16 + (l & 15)][(l >> 4)*8];
      al[m] = *(const half8*)&Al[wm + m*16 + (l & 15)][(l >> 4)*8];
    }
    #pragma unroll
    for (int n = 0; n < 4; ++n){
      bh[n] = *(const half8*)&Bh[wn + n*16 + (l & 15)][(l >> 4)*8];
      bl[n] = *(const half8*)&Bl[wn + n*16 + (l & 15)][(l >> 4)*8];
    }
    #pragma unroll
    for (int m = 0; m < 4; ++m)
      #pragma unroll
      for (int n = 0; n < 4; ++n){
        acc1[m][n] = __builtin_amdgcn_mfma_f32_16x16x32_f16(ah[m], bh[n], acc1[m][n], 0, 0, 0);
        acc2[m][n] = __builtin_amdgcn_mfma_f32_16x16x32_f16(ah[m], bl[n], acc2[m][n], 0, 0, 0);
        acc2[m][n] = __builtin_amdgcn_mfma_f32_16x16x32_f16(al[m], bh[n], acc2[m][n], 0, 0, 0);
      }
    __syncthreads();
  }
  #pragma unroll
  for (int m = 0; m < 4; ++m)
    #pragma unroll
    for (int n = 0; n < 4; ++n)
      #pragma unroll
      for (int q = 0; q < 4; ++q){
        int row = m0 + wm + m*16 + (l >> 4)*4 + q;
        int col = n0 + wn + n*16 + (l & 15);
        float v = acc1[m][n][q] + acc2[m][n][q]*INV_SCL + encb[col];
        v = fmaxf(v, 0.f);
        _Float16 hh, hl;
        split1(v, hh, hl);
        size_t off = (size_t)row*DD + col;
        xh[off] = hh; xl[off] = hl;
      }
}

// ---------------- persistent recurrence kernel ----------------
// 264 blocks launched, 132 active (4 mt x 33 js), 512 threads (8 waves).
// XCD pinning (bid&7 round-robin heuristic): strips 0..31 -> xcd js&7 (4 each);
// strip 32's four mt-blocks -> xcds 1,3,5,7 (balanced 16/17 blocks per XCD).
// Staging: global_load_lds, 4 LDS slots, depth-3, counted vmcnt, swizzled blocks.
// Wave wv: M-rows 16*(wv&3).., gates 2*(wv>>2)..+1 (6 MFMA/slab); gbuf exchange.
__launch_bounds__(512, 4)
__global__ void k_recur(_Float16* xh, _Float16* xl,
                        _Float16* h1h0, _Float16* h1l0,
                        _Float16* h1h1, _Float16* h1l1,
                        const _Float16* __restrict__ Wh0, const _Float16* __restrict__ Wl0,
                        const _Float16* __restrict__ Wh1, const _Float16* __restrict__ Wl1,
                        const float* __restrict__ bias0, const float* __restrict__ bias1,
                        const int* __restrict__ term, int* flags,
                        const _Float16* __restrict__ zp){
  __shared__ _Float16 S[4][4][64][32];   // [slot][plane 0=Ah 1=Al 2=Bh 3=Bl][row][col]
  __shared__ float gbuf[4][64][16];

  const int tid = threadIdx.x, wv = tid >> 6, l = tid & 63;
  const int b = blockIdx.x;
  const int xcd = b & 7, slot_id = b >> 3;
  int mt, js;
  if (slot_id < 16){ js = xcd + 8*(slot_id >> 2); mt = slot_id & 3; }
  else if (slot_id == 16 && (xcd & 1)){ js = 32; mt = xcd >> 1; }
  else return;
  const int m0 = mt*64, j0 = js*16;

  // ---- staging geometry: wave wv stages chunks {2wv, 2wv+1} of the 16KB slab ----
  const int c0 = 2*wv, c1 = 2*wv + 1;
  const int plA = (wv < 2) ? 0 : 1;          // waves 0,1: Ah ; 2,3: Al
  const int plB = (wv < 6) ? 2 : 3;          // waves 4,5: Bh ; 6,7: Bl
  const int rb0 = (c0 & 3)*16, rb1 = (c1 & 3)*16;
  const int row0 = rb0 + (l >> 2), row1 = rb1 + (l >> 2);
  const int gblk0 = (l & 3) ^ swz(row0), gblk1 = (l & 3) ^ swz(row1);
  const size_t aoff0 = (size_t)(m0 + row0)*DD, aoff1 = (size_t)(m0 + row1)*DD;
  const size_t boff0 = (size_t)((row0 >> 4)*DD + j0 + (row0 & 15))*KK;
  const size_t boff1 = (size_t)((row1 >> 4)*DD + j0 + (row1 & 15))*KK;

  // ---- compute geometry: wave wv -> M-tile (wv&3), gates g0, g0+1 ----
  const int mrow = (wv & 3)*16, g0 = (wv >> 2)*2;
  const int frow = mrow + (l & 15);
  const int fbA = ((l >> 4) ^ swz(frow))*8;
  const int brw0 = g0*16 + (l & 15), brw1 = brw0 + 16;
  const int fbB0 = ((l >> 4) ^ swz(brw0))*8, fbB1 = ((l >> 4) ^ swz(brw1))*8;

  // ---- epilogue slots (2 per thread) ----
  const int er0 = tid >> 4, ec = tid & 15, er1 = er0 + 32;
  const int jc = j0 + ec;

  float c1r[2] = {0.f, 0.f}, c2r[2] = {0.f, 0.f};
  f32x4 accm[2], accc[2];

  auto flag_wait = [&](int idx){
    if (tid == 0){
      while (__hip_atomic_load(&flags[idx], __ATOMIC_RELAXED, __HIP_MEMORY_SCOPE_AGENT) < 33)
        __builtin_amdgcn_s_sleep(1);
    }
    __builtin_amdgcn_s_barrier();
    __builtin_amdgcn_sched_barrier(0);
  };
  auto flag_post = [&](int idx){
    asm volatile("s_waitcnt vmcnt(0)" ::: "memory");
    __builtin_amdgcn_s_barrier();
    if (tid == 0)
      __hip_atomic_fetch_add(&flags[idx], 1, __ATOMIC_RELAXED, __HIP_MEMORY_SCOPE_AGENT);
  };

  auto run_phase = [&](bool isL1,
                       const _Float16* p1h, const _Float16* p1l,
                       const _Float16* p2h, const _Float16* p2l,
                       bool nd0, bool nd1,
                       const _Float16* Wh, const _Float16* Wl,
                       int wA_i, int wA_f, int wB_i, int wB_f){
    #pragma unroll
    for (int g = 0; g < 2; ++g)
      #pragma unroll
      for (int q = 0; q < 4; ++q){ accm[g][q] = 0.f; accc[g][q] = 0.f; }

    const _Float16* PA1 = (wv < 2) ? p1h : p1l;
    const _Float16* PA2 = (wv < 2) ? p2h : p2l;
    const _Float16* PB  = (wv < 6) ? Wh : Wl;

    auto issue = [&](int i){
      if (i == wA_i && wA_f >= 0) flag_wait(wA_f);
      if (i == wB_i && wB_f >= 0) flag_wait(wB_f);
      const int s = isL1 ? (i < 16 ? 17 + i : i - 16) : i;
      const int slot = i & 3;
      const int col0 = s*32 + gblk0*8;
      const int col1 = s*32 + gblk1*8;
      if (wv < 4){
        const _Float16* src0 = (col0 < DD) ? PA1 + aoff0 + col0
                                           : (nd0 ? PA2 + aoff0 + (col0 - DD) : zp);
        const _Float16* src1 = (col1 < DD) ? PA1 + aoff1 + col1
                                           : (nd1 ? PA2 + aoff1 + (col1 - DD) : zp);
        _Float16* d0 = (_Float16*)&S[slot][plA][rb0][0];
        _Float16* d1 = (_Float16*)&S[slot][plA][rb1][0];
        if (isL1 || s >= 16){ GLOAD_LDS(src0, d0, 17); GLOAD_LDS(src1, d1, 17); }
        else                { GLOAD_LDS(src0, d0, 0);  GLOAD_LDS(src1, d1, 0);  }
      } else {
        GLOAD_LDS(PB + boff0 + col0, (_Float16*)&S[slot][plB][rb0][0], 0);
        GLOAD_LDS(PB + boff1 + col1, (_Float16*)&S[slot][plB][rb1][0], 0);
      }
    };

    issue(0); issue(1); issue(2);
    #pragma unroll 1
    for (int i = 0; i < 33; ++i){
      if (i <= 30)      asm volatile("s_waitcnt vmcnt(4)" ::: "memory");
      else if (i == 31) asm volatile("s_waitcnt vmcnt(2)" ::: "memory");
      else              asm volatile("s_waitcnt vmcnt(0)" ::: "memory");
      __builtin_amdgcn_s_barrier();
      __builtin_amdgcn_sched_barrier(0);
      if (i + 3 < 33) issue(i + 3);
      const int slot = i & 3;
      half8 fah = *(const half8*)&S[slot][0][frow][fbA];
      half8 fal = *(const half8*)&S[slot][1][frow][fbA];
      half8 fbh0 = *(const half8*)&S[slot][2][brw0][fbB0];
      half8 fbl0 = *(const half8*)&S[slot][3][brw0][fbB0];
      half8 fbh1 = *(const half8*)&S[slot][2][brw1][fbB1];
      half8 fbl1 = *(const half8*)&S[slot][3][brw1][fbB1];
      accm[0] = __builtin_amdgcn_mfma_f32_16x16x32_f16(fah, fbh0, accm[0], 0, 0, 0);
      accc[0] = __builtin_amdgcn_mfma_f32_16x16x32_f16(fah, fbl0, accc[0], 0, 0, 0);
      accc[0] = __builtin_amdgcn_mfma_f32_16x16x32_f16(fal, fbh0, accc[0], 0, 0, 0);
      accm[1] = __builtin_amdgcn_mfma_f32_16x16x32_f16(fah, fbh1, accm[1], 0, 0, 0);
      accc[1] = __builtin_amdgcn_mfma_f32_16x16x32_f16(fah, fbl1, accc[1], 0, 0, 0);
      accc[1] = __builtin_amdgcn_mfma_f32_16x16x32_f16(fal, fbh1, accc[1], 0, 0, 0);
    }
  };

  auto epilogue = [&](const float* bias, float* cr, _Float16* dh, _Float16* dl,
                      const int* term_t){
    #pragma unroll
    for (int gi = 0; gi < 2; ++gi)
      #pragma unroll
      for (int q = 0; q < 4; ++q)
        gbuf[g0 + gi][mrow + (l >> 4)*4 + q][l & 15] = accm[gi][q] + accc[gi][q]*INV_SCL;
    __syncthreads();
    #pragma unroll
    for (int p = 0; p < 2; ++p){
      const int er = p ? er1 : er0;
      const int row = m0 + er;
      float iv = gbuf[0][er][ec] + bias[jc];
      float fv = gbuf[1][er][ec] + bias[DD + jc];
      float gv = gbuf[2][er][ec] + bias[2*DD + jc];
      float ov = gbuf[3][er][ec] + bias[3*DD + jc];
      float cp = (term_t[row] == 0) ? cr[p] : 0.f;
      float cn = sigf(fv)*cp + sigf(iv)*tanhf(gv);
      float hn = sigf(ov)*tanhf(cn);
      cr[p] = cn;
      _Float16 hh, hl;
      split1(hn, hh, hl);
      size_t off = (size_t)row*DD + jc;
      __hip_atomic_store((unsigned short*)(dh + off), __builtin_bit_cast(unsigned short, hh),
                         __ATOMIC_RELAXED, __HIP_MEMORY_SCOPE_AGENT);
      __hip_atomic_store((unsigned short*)(dl + off), __builtin_bit_cast(unsigned short, hl),
                         __ATOMIC_RELAXED, __HIP_MEMORY_SCOPE_AGENT);
    }
  };

  _Float16* h1h[2] = {h1h0, h1h1};
  _Float16* h1l[2] = {h1l0, h1l1};

  #pragma unroll 1
  for (int t = 0; t < TT; ++t){
    const int* term_t = term + t*BB;
    const bool nd0 = (t > 0) && (term_t[m0 + row0] == 0);
    const bool nd1 = (t > 0) && (term_t[m0 + row1] == 0);
    _Float16* xth = xh + (size_t)t*BB*DD;
    _Float16* xtl = xl + (size_t)t*BB*DD;
    const _Float16* xph = xh + (size_t)(t > 0 ? t-1 : 0)*BB*DD;
    const _Float16* xpl = xl + (size_t)(t > 0 ? t-1 : 0)*BB*DD;

    // ===== layer 0: gates = [x(t) | h1(t-1)*nd] @ W0^T =====
    run_phase(false, xth, xtl, h1h[(t+1)&1], h1l[(t+1)&1], nd0, nd1, Wh0, Wl0,
              16, (t >= 1) ? (t-1)*8 + mt : -1, -1, -1);
    if (t >= 2) flag_wait((t-2)*8 + 4 + mt);           // WAR on h1 buffer t&1
    epilogue(bias0, c1r, h1h[t&1], h1l[t&1], term_t);
    flag_post(t*8 + mt);

    // ===== layer 1: gates = [h1(t) | h2(t-1)*nd] @ W1^T ; h2(t-1)=x[t-1] alias =====
    run_phase(true, h1h[t&1], h1l[t&1], xph, xpl, nd0, nd1, Wh1, Wl1,
              0, (t >= 1) ? (t-1)*8 + 4 + mt : -1,
              16, t*8 + mt);
    epilogue(bias1, c2r, xth, xtl, term_t);            // h2(t) overwrites x[t]
    flag_post(t*8 + 4 + mt);
  }
}

// ---------------- heads: logits/baseline/action ----------------
__launch_bounds__(256)
__global__ void k_heads(const _Float16* __restrict__ oh, const _Float16* __restrict__ ol,
                        const float* __restrict__ polw, const float* __restrict__ basew,
                        const float* __restrict__ polb, const float* __restrict__ baseb,
                        float* __restrict__ dout){
  __shared__ _Float16 Ah[128][40], Al[128][40];
  __shared__ _Float16 Bh[16][552], Bl[16][552];
  const int bid = blockIdx.x;
  const int tid = threadIdx.x, w = tid >> 6, l = tid & 63;
  const int m0 = bid*128;

  for (int i = tid; i < 16*544; i += 256){
    int r = i / 544, c = i % 544;
    float v = 0.f;
    if (c < DD) v = (r < NA) ? polw[r*DD + c] : basew[c];
    split1(v, Bh[r][c], Bl[r][c]);
  }
  __syncthreads();

  f32x4 acc1[2], acc2[2];
  #pragma unroll
  for (int m = 0; m < 2; ++m)
    #pragma unroll
    for (int q = 0; q < 4; ++q){ acc1[m][q]=0.f; acc2[m][q]=0.f; }

  for (int it = 0; it < 17; ++it){
    const int k0 = it*32;
    {
      int row = tid >> 1, c0 = (tid & 1)*16;
      size_t off = (size_t)(m0+row)*DD + k0 + c0;   // overreads pad; B=0 there
      *(half8*)&Ah[row][c0]   = *(const half8*)(oh + off);
      *(half8*)&Ah[row][c0+8] = *(const half8*)(oh + off + 8);
      *(half8*)&Al[row][c0]   = *(const half8*)(ol + off);
      *(half8*)&Al[row][c0+8] = *(const half8*)(ol + off + 8);
    }
    __syncthreads();
    half8 fbh = *(const half8*)&Bh[l & 15][k0 + (l >> 4)*8];
    half8 fbl = *(const half8*)&Bl[l & 15][k0 + (l >> 4)*8];
    #pragma unroll
    for (int m = 0; m < 2; ++m){
      half8 fah = *(const half8*)&Ah[w*32 + m*16 + (l & 15)][(l >> 4)*8];
      half8 fal = *(const half8*)&Al[w*32 + m*16 + (l & 15)][(l >> 4)*8];
      acc1[m] = __builtin_amdgcn_mfma_f32_16x16x32_f16(fah, fbh, acc1[m], 0, 0, 0);
      acc2[m] = __builtin_amdgcn_mfma_f32_16x16x32_f16(fah, fbl, acc2[m], 0, 0, 0);
      acc2[m] = __builtin_amdgcn_mfma_f32_16x16x32_f16(fal, fbh, acc2[m], 0, 0, 0);
    }
    __syncthreads();
  }

  const int a = l & 15;
  const size_t base_off = (size_t)TT*BB*NA;
  const size_t act_off  = base_off + (size_t)TT*BB;
  #pragma unroll
  for (int m = 0; m < 2; ++m)
    #pragma unroll
    for (int q = 0; q < 4; ++q){
      int r = m0 + w*32 + m*16 + (l >> 4)*4 + q;
      float v = acc1[m][q] + acc2[m][q]*INV_SCL + ((a < NA) ? polb[a] : baseb[0]);
      float key = (a < NA) ? v : -3.4e38f;
      int ki = a;
      #pragma unroll
      for (int s = 1; s < 16; s <<= 1){
        float ov = __shfl_xor(key, s, 64);
        int   oi = __shfl_xor(ki,  s, 64);
        if (ov > key || (ov == key && oi < ki)){ key = ov; ki = oi; }
      }
      if (a < NA) dout[(size_t)r*NA + a] = v;
      if (a == NA) dout[base_off + r] = v;
      if (a == 0)  dout[act_off + r] = (float)ki;
    }
}

// ---------------- launch ----------------
extern "C" void kernel_launch(void* const* d_in, const int* in_sizes, int n_in,
                              void* d_out, int out_size, void* d_ws, size_t ws_size,
                              hipStream_t stream){
  const float* obs        = (const float*)d_in[0];
  const int*   last_act   = (const int*)  d_in[1];
  const float* reward     = (const float*)d_in[2];
  const int*   terminated = (const int*)  d_in[3];
  const float* enc_w      = (const float*)d_in[4];
  const float* enc_b      = (const float*)d_in[5];
  const float* w_ih0      = (const float*)d_in[6];
  const float* w_hh0      = (const float*)d_in[7];
  const float* b_ih0      = (const float*)d_in[8];
  const float* b_hh0      = (const float*)d_in[9];
  const float* w_ih1      = (const float*)d_in[10];
  const float* w_hh1      = (const float*)d_in[11];
  const float* b_ih1      = (const float*)d_in[12];
  const float* b_hh1      = (const float*)d_in[13];
  const float* pol_w      = (const float*)d_in[14];
  const float* pol_b      = (const float*)d_in[15];
  const float* base_w     = (const float*)d_in[16];
  const float* base_b     = (const float*)d_in[17];

  char* ws = (char*)d_ws;
  size_t o = 0;
  auto alloc = [&](size_t bytes){ size_t r = o; o += (bytes + 255) & ~(size_t)255; return r; };

  _Float16* Wh0   = (_Float16*)(ws + alloc((size_t)GG*KK*2));
  _Float16* Wl0   = (_Float16*)(ws + alloc((size_t)GG*KK*2));
  _Float16* Wh1   = (_Float16*)(ws + alloc((size_t)GG*KK*2));
  _Float16* Wl1   = (_Float16*)(ws + alloc((size_t)GG*KK*2));
  float* bias0    = (float*)(ws + alloc((size_t)GG*4));
  float* bias1    = (float*)(ws + alloc((size_t)GG*4));
  _Float16* ench  = (_Float16*)(ws + alloc((size_t)FEATD*OBSD*2));
  _Float16* encl  = (_Float16*)(ws + alloc((size_t)FEATD*OBSD*2));
  _Float16* xh    = (_Float16*)(ws + alloc((size_t)TT*BB*DD*2 + 4096));  // x / h2-out hi
  _Float16* xl    = (_Float16*)(ws + alloc((size_t)TT*BB*DD*2 + 4096));  // lo plane
  _Float16* h1h0  = (_Float16*)(ws + alloc((size_t)BB*DD*2));
  _Float16* h1l0  = (_Float16*)(ws + alloc((size_t)BB*DD*2));
  _Float16* h1h1  = (_Float16*)(ws + alloc((size_t)BB*DD*2));
  _Float16* h1l1  = (_Float16*)(ws + alloc((size_t)BB*DD*2));
  int*   flags    = (int*)(ws + alloc((size_t)TT*8*4 + 256));   // + zero page
  _Float16* zp    = (_Float16*)((char*)flags + TT*8*4);

  hipMemsetAsync(flags, 0, (size_t)TT*8*4 + 256, stream);

  k_prep_w<<<2048, 256, 0, stream>>>(w_ih0, w_hh0, b_ih0, b_hh0, Wh0, Wl0, bias0);
  k_prep_w<<<2048, 256, 0, stream>>>(w_ih1, w_hh1, b_ih1, b_hh1, Wh1, Wl1, bias1);
  k_conv_encw<<<2048, 256, 0, stream>>>(enc_w, ench, encl);
  k_fill_extra<<<TT*BB/256, 256, 0, stream>>>(reward, last_act, xh, xl);

  dim3 eg(TT*BB/128, FEATD/128);
  k_encoder<<<eg, 256, 0, stream>>>(obs, ench, encl, enc_b, xh, xl);

  k_recur<<<264, 512, 0, stream>>>(xh, xl, h1h0, h1l0, h1h1, h1l1,
                                   Wh0, Wl0, Wh1, Wl1, bias0, bias1,
                                   terminated, flags, zp);

  k_heads<<<TT*BB/128, 256, 0, stream>>>(xh, xl, pol_w, base_w, pol_b, base_b, (float*)d_out);
}